// Round 1
// baseline (2157.308 us; speedup 1.0000x reference)
//
#include <hip/hip_runtime.h>
#include <hip/hip_bf16.h>

// PCA layer: B=16, N=65536 (256x256), C=64, K=32.
// Strategy: replicate LAPACK ssyevd (ssytd2 + sstedc D&C + back-transform) in fp64
// so eigenvector SIGNS match the numpy/LAPACK reference. Everything else is
// straightforward: Gram/mean pass, then projection pass.

#define ZS(r,c) Zsh[(r)*65+(c)]

__device__ __forceinline__ double fsign(double a, double b){ return (b >= 0.0) ? fabs(a) : -fabs(a); }
__device__ __forceinline__ double slapy2(double x, double y){ return sqrt(x*x + y*y); }

__device__ __forceinline__ void slartg(double f, double g, double& cs, double& sn, double& r){
  if (g == 0.0){ cs = 1.0; sn = 0.0; r = f; }
  else if (f == 0.0){ cs = 0.0; sn = fsign(1.0, g); r = fabs(g); }
  else {
    double d = sqrt(f*f + g*g);
    cs = fabs(f)/d;
    r  = fsign(d, f);
    sn = g/r;
  }
}

__device__ __forceinline__ void slaev2(double a, double b, double c,
                                       double& rt1, double& rt2, double& cs1, double& sn1){
  double sm = a + c, df = a - c, adf = fabs(df), tb = b + b, ab = fabs(tb);
  double acmx, acmn, rt, cs, ct, acs, tn; int sgn1, sgn2;
  if (fabs(a) > fabs(c)) { acmx = a; acmn = c; } else { acmx = c; acmn = a; }
  if (adf > ab)      rt = adf*sqrt(1.0 + (ab/adf)*(ab/adf));
  else if (adf < ab) rt = ab*sqrt(1.0 + (adf/ab)*(adf/ab));
  else               rt = ab*sqrt(2.0);
  if (sm < 0.0){ rt1 = 0.5*(sm - rt); sgn1 = -1; rt2 = (acmx/rt1)*acmn - (b/rt1)*b; }
  else if (sm > 0.0){ rt1 = 0.5*(sm + rt); sgn1 = 1; rt2 = (acmx/rt1)*acmn - (b/rt1)*b; }
  else { rt1 = 0.5*rt; rt2 = -0.5*rt; sgn1 = 1; }
  if (df >= 0.0){ cs = df + rt; sgn2 = 1; } else { cs = df - rt; sgn2 = -1; }
  acs = fabs(cs);
  if (acs > ab){ ct = -tb/cs; sn1 = 1.0/sqrt(1.0 + ct*ct); cs1 = ct*sn1; }
  else {
    if (ab == 0.0){ cs1 = 1.0; sn1 = 0.0; }
    else { tn = -cs/tb; cs1 = 1.0/sqrt(1.0 + tn*tn); sn1 = tn*cs1; }
  }
  if (sgn1 == sgn2){ tn = cs1; cs1 = -sn1; sn1 = tn; }
}

__device__ __forceinline__ double wave_sum(double v){
  #pragma unroll
  for (int off = 32; off > 0; off >>= 1) v += __shfl_xor(v, off);
  return v;
}

// ---------- ssteqr('I') on a 16x16 diagonal block of Zsh, faithful transcription ----------
__device__ void steqr16(double* dd, double* ee, double* Zsh, int b0, int tid,
                        double* wc, double* wsn)
{
#define DQ(i) dd[(i)-1]
#define EQ(i) ee[(i)-1]
  const int n = 16;
  const double eps = 5.9604644775390625e-8;     // slamch('E') fp32
  const double eps2 = eps*eps;
  const double safmin = 1.1754943508222875e-38; // slamch('S') fp32
  const int nmaxit = n*30;
  int jtot = 0, l1 = 1, nm1 = n-1;
  int l, lsv, lend, lendsv, m, i;
  double p, g, r, s, c, f, b2, rt1, rt2, anorm, tst;

L10:
  if (l1 > n) goto L160;
  if (l1 > 1) EQ(l1-1) = 0.0;
  if (l1 <= nm1){
    for (m = l1; m <= nm1; ++m){
      tst = fabs(EQ(m));
      if (tst == 0.0) goto L30;
      if (tst <= (sqrt(fabs(DQ(m)))*sqrt(fabs(DQ(m+1))))*eps){ EQ(m) = 0.0; goto L30; }
    }
  }
  m = n;
L30:
  l = l1; lsv = l; lend = m; lendsv = lend; l1 = m+1;
  if (lend == l) goto L10;
  anorm = 0.0;
  for (i = l; i <= lend; ++i) anorm = fmax(anorm, fabs(DQ(i)));
  for (i = l; i <  lend; ++i) anorm = fmax(anorm, fabs(EQ(i)));
  if (anorm == 0.0) goto L10;
  // (scaling skipped: anorm is O(1) for this data, within [ssfmin, ssfmax])
  if (fabs(DQ(lend)) < fabs(DQ(l))){ lend = lsv; l = lendsv; }
  if (lend > l){
    // ------------------ QL iteration ------------------
L40:
    if (l != lend){
      for (m = l; m <= lend-1; ++m){
        tst = fabs(EQ(m)); tst = tst*tst;
        if (tst <= (eps2*fabs(DQ(m)))*fabs(DQ(m+1)) + safmin) goto L60;
      }
    }
    m = lend;
L60:
    if (m < lend) EQ(m) = 0.0;
    p = DQ(l);
    if (m == l) goto L80;
    if (m == l+1){
      slaev2(DQ(l), EQ(l), DQ(l+1), rt1, rt2, c, s);
      if (tid < 16){
        double t = ZS(b0+tid, b0+l);
        ZS(b0+tid, b0+l)   = c*t - s*ZS(b0+tid, b0+l-1);
        ZS(b0+tid, b0+l-1) = s*t + c*ZS(b0+tid, b0+l-1);
      }
      DQ(l) = rt1; DQ(l+1) = rt2; EQ(l) = 0.0;
      l += 2;
      if (l <= lend) goto L40;
      goto L140;
    }
    if (jtot == nmaxit) goto L140;
    jtot++;
    g = (DQ(l+1)-p)/(2.0*EQ(l));
    r = slapy2(g, 1.0);
    g = DQ(m) - p + (EQ(l)/(g + fsign(r, g)));
    s = 1.0; c = 1.0; p = 0.0;
    for (i = m-1; i >= l; --i){
      f = s*EQ(i); b2 = c*EQ(i);
      slartg(g, f, c, s, r);
      if (i != m-1) EQ(i+1) = r;
      g = DQ(i+1) - p;
      r = (DQ(i)-g)*s + 2.0*c*b2;
      p = s*r;
      DQ(i+1) = g + p;
      g = c*r - b2;
      wc[i] = c; wsn[i] = -s;
    }
    for (int i2 = m-1; i2 >= l; --i2){   // slasr 'R','V','B'
      double cc = wc[i2], ssv = wsn[i2];
      if (tid < 16){
        double t = ZS(b0+tid, b0+i2);
        ZS(b0+tid, b0+i2)   = cc*t - ssv*ZS(b0+tid, b0+i2-1);
        ZS(b0+tid, b0+i2-1) = ssv*t + cc*ZS(b0+tid, b0+i2-1);
      }
    }
    DQ(l) = DQ(l) - p;
    EQ(l) = g;
    goto L40;
L80:
    DQ(l) = p;
    l++;
    if (l <= lend) goto L40;
    goto L140;
  } else {
    // ------------------ QR iteration ------------------
L90:
    if (l != lend){
      for (m = l; m >= lend+1; --m){
        tst = fabs(EQ(m-1)); tst = tst*tst;
        if (tst <= (eps2*fabs(DQ(m)))*fabs(DQ(m-1)) + safmin) goto L110;
      }
    }
    m = lend;
L110:
    if (m > lend) EQ(m-1) = 0.0;
    p = DQ(l);
    if (m == l) goto L130;
    if (m == l-1){
      slaev2(DQ(l-1), EQ(l-1), DQ(l), rt1, rt2, c, s);
      if (tid < 16){
        double t = ZS(b0+tid, b0+l-1);
        ZS(b0+tid, b0+l-1) = c*t - s*ZS(b0+tid, b0+l-2);
        ZS(b0+tid, b0+l-2) = s*t + c*ZS(b0+tid, b0+l-2);
      }
      DQ(l-1) = rt1; DQ(l) = rt2; EQ(l-1) = 0.0;
      l -= 2;
      if (l >= lend) goto L90;
      goto L140;
    }
    if (jtot == nmaxit) goto L140;
    jtot++;
    g = (DQ(l-1)-p)/(2.0*EQ(l-1));
    r = slapy2(g, 1.0);
    g = DQ(m) - p + (EQ(l-1)/(g + fsign(r, g)));
    s = 1.0; c = 1.0; p = 0.0;
    for (i = m; i <= l-1; ++i){
      f = s*EQ(i); b2 = c*EQ(i);
      slartg(g, f, c, s, r);
      if (i != m) EQ(i-1) = r;
      g = DQ(i) - p;
      r = (DQ(i+1)-g)*s + 2.0*c*b2;
      p = s*r;
      DQ(i) = g + p;
      g = c*r - b2;
      wc[i] = c; wsn[i] = s;
    }
    for (int i2 = m; i2 <= l-1; ++i2){   // slasr 'R','V','F'
      double cc = wc[i2], ssv = wsn[i2];
      if (tid < 16){
        double t = ZS(b0+tid, b0+i2);
        ZS(b0+tid, b0+i2)   = cc*t - ssv*ZS(b0+tid, b0+i2-1);
        ZS(b0+tid, b0+i2-1) = ssv*t + cc*ZS(b0+tid, b0+i2-1);
      }
    }
    DQ(l) = DQ(l) - p;
    EQ(l-1) = g;
    goto L90;
L130:
    DQ(l) = p;
    l--;
    if (l >= lend) goto L90;
    goto L140;
  }
L140:
  if (jtot < nmaxit) goto L10;
L160:
  // selection sort ascending with column swaps (as in ssteqr)
  for (int ii = 2; ii <= n; ++ii){
    int i3 = ii-1, k2 = i3;
    p = DQ(i3);
    for (int j = ii; j <= n; ++j) if (DQ(j) < p){ k2 = j; p = DQ(j); }
    if (k2 != i3){
      DQ(k2) = DQ(i3); DQ(i3) = p;
      if (tid < 16){
        double t = ZS(b0+tid, b0+i3-1);
        ZS(b0+tid, b0+i3-1) = ZS(b0+tid, b0+k2-1);
        ZS(b0+tid, b0+k2-1) = t;
      }
    }
  }
#undef DQ
#undef EQ
}

// ---------- slaed1/slaed2/slaed3 merge, materialized-sorted form ----------
template<int N1>
__device__ void merge_dc(double* Zsh, double* dfull, int off, double rho_in, int tid,
                         double* zz, double* dl, double* ww, double* mu, double* wt,
                         int* idxm, int* sv, int* tl, int* fperm)
{
  const int NM = 2*N1;
  const double eps32 = 5.9604644775390625e-8;
  double col[NM > 32 ? 64 : 32];

  // z-vector: last row of Q1, first row of Q2
  if (tid < N1)       zz[tid] = ZS(off+N1-1, off+tid);
  else if (tid < NM)  zz[tid] = ZS(off+N1,   off+tid);
  __syncthreads();
  if (rho_in < 0.0 && tid >= N1 && tid < NM) zz[tid] = -zz[tid];
  __syncthreads();
  if (tid < NM) zz[tid] *= 0.70710678118654752440;
  __syncthreads();
  double rho = fabs(2.0*rho_in);

  // merged ascending order (both halves already ascending), ties -> first half
  {
    int i1 = 0, i2 = 0, t = 0;
    while (i1 < N1 && i2 < N1){
      if (dfull[off+i1] <= dfull[off+N1+i2]) idxm[t++] = i1++;
      else                                   idxm[t++] = N1 + (i2++);
    }
    while (i1 < N1) idxm[t++] = i1++;
    while (i2 < N1) idxm[t++] = N1 + (i2++);
  }
  double dmax = 0.0, zmax = 0.0;
  for (int i = 0; i < NM; ++i){ dmax = fmax(dmax, fabs(dfull[off+i])); zmax = fmax(zmax, fabs(zz[i])); }
  double tol = 8.0*eps32*fmax(dmax, zmax);

  if (rho*zmax <= tol){
    // everything deflates: just sort ascending
    double dnj = 0.0;
    if (tid < NM){
      int s0 = idxm[tid];
      dnj = dfull[off+s0];
      #pragma unroll
      for (int r = 0; r < NM; ++r) col[r] = ZS(off+r, off+s0);
    }
    __syncthreads();
    if (tid < NM){
      #pragma unroll
      for (int r = 0; r < NM; ++r) ZS(off+r, off+tid) = col[r];
      dfull[off+tid] = dnj;
    }
    __syncthreads();
    return;
  }

  // ---- slaed2 deflation scan (redundant-uniform on all lanes) ----
  int K = 0, nd = 0;
  {
    int have = 0, pj = 0;
    for (int t = 0; t < NM; ++t){
      int nj = idxm[t];
      if (rho*fabs(zz[nj]) <= tol){
        for (int q = nd; q > 0; --q) tl[q] = tl[q-1];
        tl[0] = nj; nd++;
        continue;
      }
      if (!have){ pj = nj; have = 1; continue; }
      {
        double sZ = zz[pj], cZ = zz[nj];
        double tau2 = slapy2(cZ, sZ);
        double tgap = dfull[off+nj] - dfull[off+pj];
        cZ /= tau2; sZ = -sZ/tau2;
        if (fabs(tgap*cZ*sZ) <= tol){
          zz[nj] = tau2; zz[pj] = 0.0;
          __syncthreads();
          if (tid < NM){
            double xq = ZS(off+tid, off+pj), yq = ZS(off+tid, off+nj);
            ZS(off+tid, off+pj) = cZ*xq + sZ*yq;
            ZS(off+tid, off+nj) = cZ*yq - sZ*xq;
          }
          __syncthreads();
          double t2 = dfull[off+pj]*cZ*cZ + dfull[off+nj]*sZ*sZ;
          double t3 = dfull[off+pj]*sZ*sZ + dfull[off+nj]*cZ*cZ;
          dfull[off+nj] = t3; dfull[off+pj] = t2;
          for (int q = nd; q > 0; --q) tl[q] = tl[q-1];
          tl[0] = pj; nd++;
          { int q = 0;
            while (q+1 < nd && dfull[off+tl[q]] < dfull[off+tl[q+1]]){
              int tt = tl[q]; tl[q] = tl[q+1]; tl[q+1] = tt; q++;
            } }
          pj = nj;
        } else {
          sv[K] = pj; dl[K] = dfull[off+pj]; ww[K] = zz[pj]; K++;
          pj = nj;
        }
      }
    }
    sv[K] = pj; dl[K] = dfull[off+pj]; ww[K] = zz[pj]; K++;
  }
  __syncthreads();

  // ---- secular equation roots (thread j solves root j) ----
  double zs2 = 0.0;
  for (int i = 0; i < K; ++i) zs2 += ww[i]*ww[i];
  if (tid < K){
    int j = tid;
    double lo = 0.0, hi = (j < K-1) ? (dl[j+1]-dl[j]) : rho*zs2;
    for (int it = 0; it < 24; ++it){
      double mid = 0.5*(lo+hi);
      if (mid == lo || mid == hi) break;
      double fv = 1.0;
      for (int i = 0; i < K; ++i) fv += rho*ww[i]*ww[i]/((dl[i]-dl[j]) - mid);
      if (fv < 0.0) lo = mid; else hi = mid;
    }
    double muv = 0.5*(lo+hi);
    for (int it = 0; it < 14; ++it){
      double fv = 1.0, fpv = 0.0;
      for (int i = 0; i < K; ++i){
        double den = (dl[i]-dl[j]) - muv;
        double inv = 1.0/den;
        double tq = rho*ww[i]*ww[i]*inv;
        fv += tq; fpv += tq*inv;
      }
      if (fv == 0.0) break;
      if (fv < 0.0) lo = muv; else hi = muv;
      double mn = muv - fv/fpv;
      if (!(mn > lo && mn < hi)) mn = 0.5*(lo+hi);
      if (mn == muv) break;
      muv = mn;
    }
    mu[tid] = muv;
  }
  __syncthreads();

  // ---- Gu z-tilde (slaed3 sign convention) ----
  if (tid < K){
    int i0 = tid;
    double prod = -mu[i0];
    for (int j = 0; j < K; ++j){
      if (j == i0) continue;
      double dij = dl[i0]-dl[j];
      prod *= (dij - mu[j])/dij;
    }
    wt[i0] = fsign(sqrt(fmax(-prod, 0.0)), ww[i0]);
  }
  __syncthreads();

  // ---- final permutation: slamrg(K asc, nd tail traversed backward) ----
  {
    int a = 0, q = nd-1, t = 0;
    while (a < K && q >= 0){
      if (dl[a]+mu[a] <= dfull[off+tl[q]]) { fperm[t++] = a; a++; }
      else { fperm[t++] = K+q; q--; }
    }
    while (a < K)  { fperm[t++] = a; a++; }
    while (q >= 0) { fperm[t++] = K+q; q--; }
  }
  __syncthreads();

  // ---- assemble new columns (each thread builds its final column in regs) ----
  double dnj = 0.0;
  if (tid < NM){
    int src = fperm[tid];
    if (src < K){
      int j = src;
      double muj = mu[j];
      double nrm = 0.0;
      for (int i = 0; i < K; ++i){
        double del = (dl[i]-dl[j]) - muj;
        double qv = wt[i]/del;
        nrm += qv*qv;
      }
      nrm = sqrt(nrm);
      #pragma unroll
      for (int r = 0; r < NM; ++r) col[r] = 0.0;
      for (int i = 0; i < K; ++i){
        double del = (dl[i]-dl[j]) - muj;
        double sval = (wt[i]/del)/nrm;
        int cq = off + sv[i];
        #pragma unroll
        for (int r = 0; r < NM; ++r) col[r] += ZS(off+r, cq)*sval;
      }
      dnj = dl[j] + muj;
    } else {
      int tq = tl[src-K];
      #pragma unroll
      for (int r = 0; r < NM; ++r) col[r] = ZS(off+r, off+tq);
      dnj = dfull[off+tq];
    }
  }
  __syncthreads();
  if (tid < NM){
    #pragma unroll
    for (int r = 0; r < NM; ++r) ZS(off+r, off+tid) = col[r];
    dfull[off+tid] = dnj;
  }
  __syncthreads();
}

// ---------------- Phase A: Gram + channel sums ----------------
__global__ __launch_bounds__(256) void cov_kernel(const float* __restrict__ x,
                                                  double* __restrict__ gram,
                                                  double* __restrict__ chsum)
{
  __shared__ __align__(16) float tile[16][64];
  const int b   = blockIdx.x >> 5;
  const int ch  = blockIdx.x & 31;
  const int tid = threadIdx.x;
  const int ti = tid >> 4, tj = tid & 15;
  const int lrow = tid >> 4, lf4 = tid & 15;
  const int cch = tid & 63, crr = tid >> 6;
  float acc[4][4];
  #pragma unroll
  for (int a = 0; a < 4; ++a)
    #pragma unroll
    for (int c = 0; c < 4; ++c) acc[a][c] = 0.f;
  float csum = 0.f;
  const int rbase = ch*2048;
  for (int r0 = 0; r0 < 2048; r0 += 16){
    const float4 v = *(const float4*)(x + (((size_t)b*65536 + rbase + r0 + lrow)*64 + lf4*4));
    __syncthreads();
    *(float4*)&tile[lrow][lf4*4] = v;
    __syncthreads();
    #pragma unroll
    for (int rr = 0; rr < 16; ++rr){
      float4 xi = *(const float4*)&tile[rr][4*ti];
      float4 xj = *(const float4*)&tile[rr][4*tj];
      acc[0][0] += xi.x*xj.x; acc[0][1] += xi.x*xj.y; acc[0][2] += xi.x*xj.z; acc[0][3] += xi.x*xj.w;
      acc[1][0] += xi.y*xj.x; acc[1][1] += xi.y*xj.y; acc[1][2] += xi.y*xj.z; acc[1][3] += xi.y*xj.w;
      acc[2][0] += xi.z*xj.x; acc[2][1] += xi.z*xj.y; acc[2][2] += xi.z*xj.z; acc[2][3] += xi.z*xj.w;
      acc[3][0] += xi.w*xj.x; acc[3][1] += xi.w*xj.y; acc[3][2] += xi.w*xj.z; acc[3][3] += xi.w*xj.w;
    }
    #pragma unroll
    for (int rr2 = 0; rr2 < 4; ++rr2) csum += tile[crr + rr2*4][cch];
  }
  double* gb = gram + (size_t)b*4096;
  #pragma unroll
  for (int a = 0; a < 4; ++a)
    #pragma unroll
    for (int c = 0; c < 4; ++c)
      atomicAdd(&gb[(4*ti+a)*64 + (4*tj+c)], (double)acc[a][c]);
  atomicAdd(&chsum[b*64 + cch], (double)csum);
}

// ---------------- Phase B: per-batch ssyevd replication ----------------
__global__ __launch_bounds__(64) void eigh_kernel(const double* __restrict__ gram,
                                                  const double* __restrict__ chsum,
                                                  double* __restrict__ AwAll,
                                                  float* __restrict__ Vt,
                                                  float* __restrict__ meanf)
{
  __shared__ double Zsh_s[64*65];
  __shared__ double ds_[64], es_[64], tau_[64], vv_[64], wv_[64];
  __shared__ double wc_[20], wsn_[20];
  __shared__ double zz_[64], dl_[64], ww_[64], mu_[64], wt_[64];
  __shared__ int idxm_[64], sv_[64], tl_[64], fp_[64];
  double* Zsh = Zsh_s;
  const int b = blockIdx.x;
  const int tid = threadIdx.x;
  double* Aw = AwAll + (size_t)b*4096;
  const double* gb = gram + (size_t)b*4096;

  // covariance (lower+upper) into Aw; mean out
  double mut = chsum[b*64+tid]*(1.0/65536.0);
  meanf[b*64+tid] = (float)mut;
  vv_[tid] = mut;
  __syncthreads();
  for (int idx = tid; idx < 4096; idx += 64){
    int i = idx >> 6, j = idx & 63;
    Aw[idx] = (gb[idx] - 65536.0*vv_[i]*vv_[j])*(1.0/65535.0);
  }
  __threadfence();
  __syncthreads();

  // ---- ssytd2 lower ----
  for (int i = 0; i < 63; ++i){
    double alpha = Aw[(i+1)*64+i];
    double xv0 = (tid >= i+2) ? Aw[tid*64+i] : 0.0;
    double xn2 = wave_sum(xv0*xv0);
    if (xn2 == 0.0){
      es_[i] = alpha;
      tau_[i] = 0.0;
    } else {
      double xnorm = sqrt(xn2);
      double beta_ = -fsign(slapy2(alpha, xnorm), alpha);
      double taui  = (beta_-alpha)/beta_;
      double invs  = 1.0/(alpha-beta_);
      if (tid >= i+2) Aw[tid*64+i] = xv0*invs;
      __syncthreads();
      vv_[tid] = (tid == i+1) ? 1.0 : ((tid >= i+2) ? Aw[tid*64+i] : 0.0);
      __syncthreads();
      double xvr = 0.0;
      if (tid >= i+1){
        for (int c2 = i+1; c2 < 64; ++c2){
          double a = (c2 <= tid) ? Aw[tid*64+c2] : Aw[c2*64+tid];
          xvr += a*vv_[c2];
        }
        xvr *= taui;
      }
      double dot = wave_sum((tid >= i+1) ? xvr*vv_[tid] : 0.0);
      double alf = -0.5*taui*dot;
      if (tid >= i+1) wv_[tid] = xvr + alf*vv_[tid];
      __syncthreads();
      if (tid >= i+1){
        double vr = vv_[tid], wr = wv_[tid];
        for (int c2 = i+1; c2 <= tid; ++c2) Aw[tid*64+c2] -= vr*wv_[c2] + wr*vv_[c2];
      }
      __syncthreads();
      es_[i] = beta_;
      tau_[i] = taui;
    }
    ds_[i] = Aw[i*64+i];
    __syncthreads();
  }
  ds_[63] = Aw[63*64+63];
  __syncthreads();

  // ---- slaed0: Z = I, cut adjustments, 4x steqr16, 3 merges ----
  for (int idx = tid; idx < 64*65; idx += 64) Zsh[idx] = 0.0;
  __syncthreads();
  ZS(tid, tid) = 1.0;
  __syncthreads();
  {
    double a15 = fabs(es_[15]), a31 = fabs(es_[31]), a47 = fabs(es_[47]);
    ds_[15] -= a15; ds_[16] -= a15;
    ds_[31] -= a31; ds_[32] -= a31;
    ds_[47] -= a47; ds_[48] -= a47;
  }
  __syncthreads();
  steqr16(ds_+0,  es_+0,  Zsh, 0,  tid, wc_, wsn_); __syncthreads();
  steqr16(ds_+16, es_+16, Zsh, 16, tid, wc_, wsn_); __syncthreads();
  steqr16(ds_+32, es_+32, Zsh, 32, tid, wc_, wsn_); __syncthreads();
  steqr16(ds_+48, es_+48, Zsh, 48, tid, wc_, wsn_); __syncthreads();
  merge_dc<16>(Zsh, ds_, 0,  es_[15], tid, zz_, dl_, ww_, mu_, wt_, idxm_, sv_, tl_, fp_);
  merge_dc<16>(Zsh, ds_, 32, es_[47], tid, zz_, dl_, ww_, mu_, wt_, idxm_, sv_, tl_, fp_);
  merge_dc<32>(Zsh, ds_, 0,  es_[31], tid, zz_, dl_, ww_, mu_, wt_, idxm_, sv_, tl_, fp_);

  // ---- back-transform: Z := H1...H63 * Z (each thread owns one column) ----
  {
    int j = tid;
    for (int i = 62; i >= 0; --i){
      double taui = tau_[i];
      if (taui == 0.0) continue;
      double w = ZS(i+1, j);
      for (int r = i+2; r < 64; ++r) w += Aw[r*64+i]*ZS(r, j);
      w *= taui;
      ZS(i+1, j) -= w;
      for (int r = i+2; r < 64; ++r) ZS(r, j) -= Aw[r*64+i]*w;
    }
  }
  __syncthreads();

  // Vt[b][c][k] = V[c][63-k]  (descending top-32)
  for (int idx = tid; idx < 2048; idx += 64){
    int c2 = idx >> 5, k = idx & 31;
    Vt[(size_t)b*2048 + idx] = (float)ZS(c2, 63-k);
  }
}

// ---------------- Phase C: projection ----------------
__global__ __launch_bounds__(256) void proj_kernel(const float* __restrict__ x,
                                                   const float* __restrict__ Vt,
                                                   const float* __restrict__ meanf,
                                                   float* __restrict__ out)
{
  __shared__ float Vs[64][32];
  __shared__ float ms[64];
  const int b = blockIdx.x >> 8;
  const int rb = blockIdx.x & 255;
  const int tid = threadIdx.x;
  for (int idx = tid; idx < 2048; idx += 256) ((float*)Vs)[idx] = Vt[(size_t)b*2048 + idx];
  if (tid < 64) ms[tid] = meanf[b*64+tid];
  __syncthreads();
  const size_t row = (size_t)b*65536 + (size_t)rb*256 + tid;
  const float4* xr = (const float4*)(x + row*64);
  float acc[32];
  #pragma unroll
  for (int k = 0; k < 32; ++k) acc[k] = 0.f;
  #pragma unroll
  for (int c4 = 0; c4 < 16; ++c4){
    float4 xv = xr[c4];
    float t0 = xv.x - ms[4*c4+0];
    float t1 = xv.y - ms[4*c4+1];
    float t2 = xv.z - ms[4*c4+2];
    float t3 = xv.w - ms[4*c4+3];
    #pragma unroll
    for (int k = 0; k < 32; ++k) acc[k] += t0*Vs[4*c4+0][k];
    #pragma unroll
    for (int k = 0; k < 32; ++k) acc[k] += t1*Vs[4*c4+1][k];
    #pragma unroll
    for (int k = 0; k < 32; ++k) acc[k] += t2*Vs[4*c4+2][k];
    #pragma unroll
    for (int k = 0; k < 32; ++k) acc[k] += t3*Vs[4*c4+3][k];
  }
  float4* op = (float4*)(out + row*32);
  #pragma unroll
  for (int k4 = 0; k4 < 8; ++k4)
    op[k4] = make_float4(acc[4*k4], acc[4*k4+1], acc[4*k4+2], acc[4*k4+3]);
}

extern "C" void kernel_launch(void* const* d_in, const int* in_sizes, int n_in,
                              void* d_out, int out_size, void* d_ws, size_t ws_size,
                              hipStream_t stream)
{
  const float* x = (const float*)d_in[0];
  float* out = (float*)d_out;
  char* ws = (char*)d_ws;
  // ws layout (bytes):
  //   [0,       524288) gram   16x64x64 double  (atomics -> must be zeroed)
  //   [524288,  532480) chsum  16x64 double     (atomics -> must be zeroed)
  //   [532480, 1056768) Aw     16x64x64 double  (cov / reflectors)
  //   [1056768,1187840) Vt     16x64x32 float
  //   [1187840,1191936) meanf  16x64 float
  double* gram  = (double*)(ws);
  double* chsum = (double*)(ws + 524288);
  double* Aw    = (double*)(ws + 532480);
  float*  Vt    = (float*) (ws + 1056768);
  float*  mf    = (float*) (ws + 1187840);
  hipMemsetAsync(ws, 0, 532480, stream);
  cov_kernel <<<dim3(512),  dim3(256), 0, stream>>>(x, gram, chsum);
  eigh_kernel<<<dim3(16),   dim3(64),  0, stream>>>(gram, chsum, Aw, Vt, mf);
  proj_kernel<<<dim3(4096), dim3(256), 0, stream>>>(x, Vt, mf, out);
}

// Round 2
// 1408.810 us; speedup vs baseline: 1.5313x; 1.5313x over previous
//
#include <hip/hip_runtime.h>
#include <hip/hip_bf16.h>

// PCA layer: B=16, N=65536 (256x256), C=64, K=32.
// LAPACK ssyevd replication (ssytd2 + sstedc D&C + back-transform) in fp64 so
// eigenvector SIGNS match the numpy/LAPACK reference.
// R2: eigh split into 4 kernels (tridiag 16 blk / steqr16 64 blk / merge16 32 blk /
// merge32+backtransform 16 blk); matrix in LDS; reflectors via uniform global loads.

__device__ __forceinline__ double fsign(double a, double b){ return (b >= 0.0) ? fabs(a) : -fabs(a); }
__device__ __forceinline__ double slapy2(double x, double y){ return sqrt(x*x + y*y); }

__device__ __forceinline__ void slartg(double f, double g, double& cs, double& sn, double& r){
  if (g == 0.0){ cs = 1.0; sn = 0.0; r = f; }
  else if (f == 0.0){ cs = 0.0; sn = fsign(1.0, g); r = fabs(g); }
  else {
    double d = sqrt(f*f + g*g);
    cs = fabs(f)/d;
    r  = fsign(d, f);
    sn = g/r;
  }
}

__device__ __forceinline__ void slaev2(double a, double b, double c,
                                       double& rt1, double& rt2, double& cs1, double& sn1){
  double sm = a + c, df = a - c, adf = fabs(df), tb = b + b, ab = fabs(tb);
  double acmx, acmn, rt, cs, ct, acs, tn; int sgn1, sgn2;
  if (fabs(a) > fabs(c)) { acmx = a; acmn = c; } else { acmx = c; acmn = a; }
  if (adf > ab)      rt = adf*sqrt(1.0 + (ab/adf)*(ab/adf));
  else if (adf < ab) rt = ab*sqrt(1.0 + (adf/ab)*(adf/ab));
  else               rt = ab*sqrt(2.0);
  if (sm < 0.0){ rt1 = 0.5*(sm - rt); sgn1 = -1; rt2 = (acmx/rt1)*acmn - (b/rt1)*b; }
  else if (sm > 0.0){ rt1 = 0.5*(sm + rt); sgn1 = 1; rt2 = (acmx/rt1)*acmn - (b/rt1)*b; }
  else { rt1 = 0.5*rt; rt2 = -0.5*rt; sgn1 = 1; }
  if (df >= 0.0){ cs = df + rt; sgn2 = 1; } else { cs = df - rt; sgn2 = -1; }
  acs = fabs(cs);
  if (acs > ab){ ct = -tb/cs; sn1 = 1.0/sqrt(1.0 + ct*ct); cs1 = ct*sn1; }
  else {
    if (ab == 0.0){ cs1 = 1.0; sn1 = 0.0; }
    else { tn = -cs/tb; cs1 = 1.0/sqrt(1.0 + tn*tn); sn1 = tn*cs1; }
  }
  if (sgn1 == sgn2){ tn = cs1; cs1 = -sn1; sn1 = tn; }
}

__device__ __forceinline__ double wave_sum(double v){
  #pragma unroll
  for (int off = 32; off > 0; off >>= 1) v += __shfl_xor(v, off);
  return v;
}

// ---------- ssteqr('I') on a standalone 16x16 tile (ld=LDZ), faithful transcription ----------
template<int LDZ>
__device__ void steqr16(double* dd, double* ee, double* Zt, int tid,
                        double* wc, double* wsn)
{
#define DQ(i) dd[(i)-1]
#define EQ(i) ee[(i)-1]
#define ZT(r,c) Zt[(r)*LDZ+(c)]
  const int n = 16;
  const double eps = 5.9604644775390625e-8;     // slamch('E') fp32
  const double eps2 = eps*eps;
  const double safmin = 1.1754943508222875e-38; // slamch('S') fp32
  const int nmaxit = n*30;
  int jtot = 0, l1 = 1, nm1 = n-1;
  int l, lsv, lend, lendsv, m, i;
  double p, g, r, s, c, f, b2, rt1, rt2, anorm, tst;

L10:
  if (l1 > n) goto L160;
  if (l1 > 1) EQ(l1-1) = 0.0;
  if (l1 <= nm1){
    for (m = l1; m <= nm1; ++m){
      tst = fabs(EQ(m));
      if (tst == 0.0) goto L30;
      if (tst <= (sqrt(fabs(DQ(m)))*sqrt(fabs(DQ(m+1))))*eps){ EQ(m) = 0.0; goto L30; }
    }
  }
  m = n;
L30:
  l = l1; lsv = l; lend = m; lendsv = lend; l1 = m+1;
  if (lend == l) goto L10;
  anorm = 0.0;
  for (i = l; i <= lend; ++i) anorm = fmax(anorm, fabs(DQ(i)));
  for (i = l; i <  lend; ++i) anorm = fmax(anorm, fabs(EQ(i)));
  if (anorm == 0.0) goto L10;
  if (fabs(DQ(lend)) < fabs(DQ(l))){ lend = lsv; l = lendsv; }
  if (lend > l){
    // ------------------ QL iteration ------------------
L40:
    if (l != lend){
      for (m = l; m <= lend-1; ++m){
        tst = fabs(EQ(m)); tst = tst*tst;
        if (tst <= (eps2*fabs(DQ(m)))*fabs(DQ(m+1)) + safmin) goto L60;
      }
    }
    m = lend;
L60:
    if (m < lend) EQ(m) = 0.0;
    p = DQ(l);
    if (m == l) goto L80;
    if (m == l+1){
      slaev2(DQ(l), EQ(l), DQ(l+1), rt1, rt2, c, s);
      if (tid < 16){
        double t = ZT(tid, l);
        ZT(tid, l)   = c*t - s*ZT(tid, l-1);
        ZT(tid, l-1) = s*t + c*ZT(tid, l-1);
      }
      DQ(l) = rt1; DQ(l+1) = rt2; EQ(l) = 0.0;
      l += 2;
      if (l <= lend) goto L40;
      goto L140;
    }
    if (jtot == nmaxit) goto L140;
    jtot++;
    g = (DQ(l+1)-p)/(2.0*EQ(l));
    r = slapy2(g, 1.0);
    g = DQ(m) - p + (EQ(l)/(g + fsign(r, g)));
    s = 1.0; c = 1.0; p = 0.0;
    for (i = m-1; i >= l; --i){
      f = s*EQ(i); b2 = c*EQ(i);
      slartg(g, f, c, s, r);
      if (i != m-1) EQ(i+1) = r;
      g = DQ(i+1) - p;
      r = (DQ(i)-g)*s + 2.0*c*b2;
      p = s*r;
      DQ(i+1) = g + p;
      g = c*r - b2;
      wc[i] = c; wsn[i] = -s;
    }
    for (int i2 = m-1; i2 >= l; --i2){   // slasr 'R','V','B'
      double cc = wc[i2], ssv = wsn[i2];
      if (tid < 16){
        double t = ZT(tid, i2);
        ZT(tid, i2)   = cc*t - ssv*ZT(tid, i2-1);
        ZT(tid, i2-1) = ssv*t + cc*ZT(tid, i2-1);
      }
    }
    DQ(l) = DQ(l) - p;
    EQ(l) = g;
    goto L40;
L80:
    DQ(l) = p;
    l++;
    if (l <= lend) goto L40;
    goto L140;
  } else {
    // ------------------ QR iteration ------------------
L90:
    if (l != lend){
      for (m = l; m >= lend+1; --m){
        tst = fabs(EQ(m-1)); tst = tst*tst;
        if (tst <= (eps2*fabs(DQ(m)))*fabs(DQ(m-1)) + safmin) goto L110;
      }
    }
    m = lend;
L110:
    if (m > lend) EQ(m-1) = 0.0;
    p = DQ(l);
    if (m == l) goto L130;
    if (m == l-1){
      slaev2(DQ(l-1), EQ(l-1), DQ(l), rt1, rt2, c, s);
      if (tid < 16){
        double t = ZT(tid, l-1);
        ZT(tid, l-1) = c*t - s*ZT(tid, l-2);
        ZT(tid, l-2) = s*t + c*ZT(tid, l-2);
      }
      DQ(l-1) = rt1; DQ(l) = rt2; EQ(l-1) = 0.0;
      l -= 2;
      if (l >= lend) goto L90;
      goto L140;
    }
    if (jtot == nmaxit) goto L140;
    jtot++;
    g = (DQ(l-1)-p)/(2.0*EQ(l-1));
    r = slapy2(g, 1.0);
    g = DQ(m) - p + (EQ(l-1)/(g + fsign(r, g)));
    s = 1.0; c = 1.0; p = 0.0;
    for (i = m; i <= l-1; ++i){
      f = s*EQ(i); b2 = c*EQ(i);
      slartg(g, f, c, s, r);
      if (i != m) EQ(i-1) = r;
      g = DQ(i) - p;
      r = (DQ(i+1)-g)*s + 2.0*c*b2;
      p = s*r;
      DQ(i) = g + p;
      g = c*r - b2;
      wc[i] = c; wsn[i] = s;
    }
    for (int i2 = m; i2 <= l-1; ++i2){   // slasr 'R','V','F'
      double cc = wc[i2], ssv = wsn[i2];
      if (tid < 16){
        double t = ZT(tid, i2);
        ZT(tid, i2)   = cc*t - ssv*ZT(tid, i2-1);
        ZT(tid, i2-1) = ssv*t + cc*ZT(tid, i2-1);
      }
    }
    DQ(l) = DQ(l) - p;
    EQ(l-1) = g;
    goto L90;
L130:
    DQ(l) = p;
    l--;
    if (l >= lend) goto L90;
    goto L140;
  }
L140:
  if (jtot < nmaxit) goto L10;
L160:
  // selection sort ascending with column swaps (as in ssteqr)
  for (int ii = 2; ii <= n; ++ii){
    int i3 = ii-1, k2 = i3;
    p = DQ(i3);
    for (int j = ii; j <= n; ++j) if (DQ(j) < p){ k2 = j; p = DQ(j); }
    if (k2 != i3){
      DQ(k2) = DQ(i3); DQ(i3) = p;
      if (tid < 16){
        double t = ZT(tid, i3-1);
        ZT(tid, i3-1) = ZT(tid, k2-1);
        ZT(tid, k2-1) = t;
      }
    }
  }
#undef DQ
#undef EQ
#undef ZT
}

// ---------- slaed1/slaed2/slaed3 merge on a standalone NMxNM tile ----------
template<int N1, int LD>
__device__ void merge_dc(double* Z, double* dloc, double rho_in, int tid,
                         double* zz, double* dl, double* ww, double* mu, double* wt,
                         int* idxm, int* sv, int* tl, int* fperm)
{
  const int NM = 2*N1;
  const double eps32 = 5.9604644775390625e-8;
  double col[NM];

  // z-vector: last row of Q1, first row of Q2
  if (tid < N1)       zz[tid] = Z[(N1-1)*LD + tid];
  else if (tid < NM)  zz[tid] = Z[N1*LD + tid];
  __syncthreads();
  if (rho_in < 0.0 && tid >= N1 && tid < NM) zz[tid] = -zz[tid];
  __syncthreads();
  if (tid < NM) zz[tid] *= 0.70710678118654752440;
  __syncthreads();
  double rho = fabs(2.0*rho_in);

  // merged ascending order (both halves already ascending), ties -> first half
  {
    int i1 = 0, i2 = 0, t = 0;
    while (i1 < N1 && i2 < N1){
      if (dloc[i1] <= dloc[N1+i2]) idxm[t++] = i1++;
      else                         idxm[t++] = N1 + (i2++);
    }
    while (i1 < N1) idxm[t++] = i1++;
    while (i2 < N1) idxm[t++] = N1 + (i2++);
  }
  double dmax = 0.0, zmax = 0.0;
  for (int i = 0; i < NM; ++i){ dmax = fmax(dmax, fabs(dloc[i])); zmax = fmax(zmax, fabs(zz[i])); }
  double tol = 8.0*eps32*fmax(dmax, zmax);

  if (rho*zmax <= tol){
    // everything deflates: just sort ascending
    double dnj = 0.0;
    if (tid < NM){
      int s0 = idxm[tid];
      dnj = dloc[s0];
      #pragma unroll
      for (int r = 0; r < NM; ++r) col[r] = Z[r*LD + s0];
    }
    __syncthreads();
    if (tid < NM){
      #pragma unroll
      for (int r = 0; r < NM; ++r) Z[r*LD + tid] = col[r];
      dloc[tid] = dnj;
    }
    __syncthreads();
    return;
  }

  // ---- slaed2 deflation scan (redundant-uniform on all lanes) ----
  int K = 0, nd = 0;
  {
    int have = 0, pj = 0;
    for (int t = 0; t < NM; ++t){
      int nj = idxm[t];
      if (rho*fabs(zz[nj]) <= tol){
        for (int q = nd; q > 0; --q) tl[q] = tl[q-1];
        tl[0] = nj; nd++;
        continue;
      }
      if (!have){ pj = nj; have = 1; continue; }
      {
        double sZ = zz[pj], cZ = zz[nj];
        double tau2 = slapy2(cZ, sZ);
        double tgap = dloc[nj] - dloc[pj];
        cZ /= tau2; sZ = -sZ/tau2;
        if (fabs(tgap*cZ*sZ) <= tol){
          zz[nj] = tau2; zz[pj] = 0.0;
          __syncthreads();
          if (tid < NM){
            double xq = Z[tid*LD + pj], yq = Z[tid*LD + nj];
            Z[tid*LD + pj] = cZ*xq + sZ*yq;
            Z[tid*LD + nj] = cZ*yq - sZ*xq;
          }
          __syncthreads();
          double t2 = dloc[pj]*cZ*cZ + dloc[nj]*sZ*sZ;
          double t3 = dloc[pj]*sZ*sZ + dloc[nj]*cZ*cZ;
          dloc[nj] = t3; dloc[pj] = t2;
          for (int q = nd; q > 0; --q) tl[q] = tl[q-1];
          tl[0] = pj; nd++;
          { int q = 0;
            while (q+1 < nd && dloc[tl[q]] < dloc[tl[q+1]]){
              int tt = tl[q]; tl[q] = tl[q+1]; tl[q+1] = tt; q++;
            } }
          pj = nj;
        } else {
          sv[K] = pj; dl[K] = dloc[pj]; ww[K] = zz[pj]; K++;
          pj = nj;
        }
      }
    }
    sv[K] = pj; dl[K] = dloc[pj]; ww[K] = zz[pj]; K++;
  }
  __syncthreads();

  // ---- secular equation roots (thread j solves root j) ----
  double zs2 = 0.0;
  for (int i = 0; i < K; ++i) zs2 += ww[i]*ww[i];
  if (tid < K){
    int j = tid;
    double lo = 0.0, hi = (j < K-1) ? (dl[j+1]-dl[j]) : rho*zs2;
    for (int it = 0; it < 24; ++it){
      double mid = 0.5*(lo+hi);
      if (mid == lo || mid == hi) break;
      double fv = 1.0;
      for (int i = 0; i < K; ++i) fv += rho*ww[i]*ww[i]/((dl[i]-dl[j]) - mid);
      if (fv < 0.0) lo = mid; else hi = mid;
    }
    double muv = 0.5*(lo+hi);
    for (int it = 0; it < 14; ++it){
      double fv = 1.0, fpv = 0.0;
      for (int i = 0; i < K; ++i){
        double den = (dl[i]-dl[j]) - muv;
        double inv = 1.0/den;
        double tq = rho*ww[i]*ww[i]*inv;
        fv += tq; fpv += tq*inv;
      }
      if (fv == 0.0) break;
      if (fv < 0.0) lo = muv; else hi = muv;
      double mn = muv - fv/fpv;
      if (!(mn > lo && mn < hi)) mn = 0.5*(lo+hi);
      if (mn == muv) break;
      muv = mn;
    }
    mu[tid] = muv;
  }
  __syncthreads();

  // ---- Gu z-tilde (slaed3 sign convention) ----
  if (tid < K){
    int i0 = tid;
    double prod = -mu[i0];
    for (int j = 0; j < K; ++j){
      if (j == i0) continue;
      double dij = dl[i0]-dl[j];
      prod *= (dij - mu[j])/dij;
    }
    wt[i0] = fsign(sqrt(fmax(-prod, 0.0)), ww[i0]);
  }
  __syncthreads();

  // ---- final permutation: slamrg(K asc, nd tail traversed backward) ----
  {
    int a = 0, q = nd-1, t = 0;
    while (a < K && q >= 0){
      if (dl[a]+mu[a] <= dloc[tl[q]]) { fperm[t++] = a; a++; }
      else { fperm[t++] = K+q; q--; }
    }
    while (a < K)  { fperm[t++] = a; a++; }
    while (q >= 0) { fperm[t++] = K+q; q--; }
  }
  __syncthreads();

  // ---- assemble new columns (each thread builds its final column in regs) ----
  double dnj = 0.0;
  if (tid < NM){
    int src = fperm[tid];
    if (src < K){
      int j = src;
      double muj = mu[j];
      double nrm = 0.0;
      for (int i = 0; i < K; ++i){
        double del = (dl[i]-dl[j]) - muj;
        double qv = wt[i]/del;
        nrm += qv*qv;
      }
      nrm = sqrt(nrm);
      #pragma unroll
      for (int r = 0; r < NM; ++r) col[r] = 0.0;
      for (int i = 0; i < K; ++i){
        double del = (dl[i]-dl[j]) - muj;
        double sval = (wt[i]/del)/nrm;
        int cq = sv[i];
        #pragma unroll
        for (int r = 0; r < NM; ++r) col[r] += Z[r*LD + cq]*sval;
      }
      dnj = dl[j] + muj;
    } else {
      int tq = tl[src-K];
      #pragma unroll
      for (int r = 0; r < NM; ++r) col[r] = Z[r*LD + tq];
      dnj = dloc[tq];
    }
  }
  __syncthreads();
  if (tid < NM){
    #pragma unroll
    for (int r = 0; r < NM; ++r) Z[r*LD + tid] = col[r];
    dloc[tid] = dnj;
  }
  __syncthreads();
}

// ---------------- Phase A: Gram + channel sums ----------------
__global__ __launch_bounds__(256) void cov_kernel(const float* __restrict__ x,
                                                  double* __restrict__ gram,
                                                  double* __restrict__ chsum)
{
  __shared__ __align__(16) float tile[16][64];
  const int b   = blockIdx.x >> 5;
  const int ch  = blockIdx.x & 31;
  const int tid = threadIdx.x;
  const int ti = tid >> 4, tj = tid & 15;
  const int lrow = tid >> 4, lf4 = tid & 15;
  const int cch = tid & 63, crr = tid >> 6;
  float acc[4][4];
  #pragma unroll
  for (int a = 0; a < 4; ++a)
    #pragma unroll
    for (int c = 0; c < 4; ++c) acc[a][c] = 0.f;
  float csum = 0.f;
  const int rbase = ch*2048;
  for (int r0 = 0; r0 < 2048; r0 += 16){
    const float4 v = *(const float4*)(x + (((size_t)b*65536 + rbase + r0 + lrow)*64 + lf4*4));
    __syncthreads();
    *(float4*)&tile[lrow][lf4*4] = v;
    __syncthreads();
    #pragma unroll
    for (int rr = 0; rr < 16; ++rr){
      float4 xi = *(const float4*)&tile[rr][4*ti];
      float4 xj = *(const float4*)&tile[rr][4*tj];
      acc[0][0] += xi.x*xj.x; acc[0][1] += xi.x*xj.y; acc[0][2] += xi.x*xj.z; acc[0][3] += xi.x*xj.w;
      acc[1][0] += xi.y*xj.x; acc[1][1] += xi.y*xj.y; acc[1][2] += xi.y*xj.z; acc[1][3] += xi.y*xj.w;
      acc[2][0] += xi.z*xj.x; acc[2][1] += xi.z*xj.y; acc[2][2] += xi.z*xj.z; acc[2][3] += xi.z*xj.w;
      acc[3][0] += xi.w*xj.x; acc[3][1] += xi.w*xj.y; acc[3][2] += xi.w*xj.z; acc[3][3] += xi.w*xj.w;
    }
    #pragma unroll
    for (int rr2 = 0; rr2 < 4; ++rr2) csum += tile[crr + rr2*4][cch];
  }
  double* gb = gram + (size_t)b*4096;
  #pragma unroll
  for (int a = 0; a < 4; ++a)
    #pragma unroll
    for (int c = 0; c < 4; ++c)
      atomicAdd(&gb[(4*ti+a)*64 + (4*tj+c)], (double)acc[a][c]);
  atomicAdd(&chsum[b*64 + cch], (double)csum);
}

// ---------------- Phase B1: ssytd2 (dense symmetric trailing update in LDS) ----------------
__global__ __launch_bounds__(64) void tridiag_kernel(const double* __restrict__ gram,
                                                     const double* __restrict__ chsum,
                                                     double* __restrict__ dG,
                                                     double* __restrict__ eG,
                                                     double* __restrict__ tauG,
                                                     double* __restrict__ VlG,
                                                     float* __restrict__ meanG)
{
  __shared__ double As[64*65];
  __shared__ double vv_[64], wv_[64], mu_s[64], es_s[64], tau_s[64];
  const int b = blockIdx.x;
  const int tid = threadIdx.x;
  const double* gb = gram + (size_t)b*4096;

  double mval = chsum[b*64+tid]*(1.0/65536.0);
  meanG[b*64+tid] = (float)mval;
  mu_s[tid] = mval;
  __syncthreads();
  for (int idx = tid; idx < 4096; idx += 64){
    int i = idx >> 6, j = idx & 63;
    As[i*65+j] = (gb[idx] - 65536.0*mu_s[i]*mu_s[j])*(1.0/65535.0);
  }
  __syncthreads();

  for (int i = 0; i < 63; ++i){
    double alpha = As[(i+1)*65+i];
    double xv0 = (tid >= i+2) ? As[tid*65+i] : 0.0;
    double xn2 = wave_sum(xv0*xv0);
    if (xn2 == 0.0){
      es_s[i] = alpha; tau_s[i] = 0.0;
      VlG[((size_t)b*63 + i)*64 + tid] = 0.0;
      __syncthreads();
      continue;
    }
    double xnorm = sqrt(xn2);
    double betav = -fsign(slapy2(alpha, xnorm), alpha);
    double taui  = (betav-alpha)/betav;
    double invs  = 1.0/(alpha-betav);
    double vval = (tid == i+1) ? 1.0 : ((tid >= i+2) ? xv0*invs : 0.0);
    vv_[tid] = vval;
    VlG[((size_t)b*63 + i)*64 + tid] = vval;   // coalesced reflector store (transposed layout)
    __syncthreads();
    double xvr = 0.0;
    if (tid >= i+1){
      for (int c2 = i+1; c2 < 64; ++c2) xvr += As[tid*65+c2]*vv_[c2];
      xvr *= taui;
    }
    double dot = wave_sum((tid >= i+1) ? xvr*vval : 0.0);
    double alf = -0.5*taui*dot;
    wv_[tid] = (tid >= i+1) ? (xvr + alf*vval) : 0.0;
    __syncthreads();
    if (tid >= i+1){
      double vr = vval, wr = wv_[tid];
      for (int c2 = i+1; c2 < 64; ++c2) As[tid*65+c2] -= vr*wv_[c2] + wr*vv_[c2];
    }
    es_s[i] = betav; tau_s[i] = taui;
    __syncthreads();
  }
  dG[b*64+tid]   = As[tid*65+tid];
  eG[b*64+tid]   = (tid < 63) ? es_s[tid]  : 0.0;
  tauG[b*64+tid] = (tid < 63) ? tau_s[tid] : 0.0;
}

// ---------------- Phase B2: 64 independent 16x16 steqr ----------------
__global__ __launch_bounds__(64) void steqr_kernel(double* __restrict__ dG,
                                                   const double* __restrict__ eG,
                                                   double* __restrict__ Zg)
{
  __shared__ double Zt[16*17];
  __shared__ double dd[16], ee[16], wc[20], wsn[20];
  const int b = blockIdx.x >> 2, s = blockIdx.x & 3;
  const int tid = threadIdx.x;

  // load tridiag segment + D&C rank-one cut adjustments
  {
    double dv = (tid < 16) ? dG[b*64 + 16*s + tid] : 0.0;
    if (tid == 0  && s > 0) dv -= fabs(eG[b*64 + 16*s - 1]);
    if (tid == 15 && s < 3) dv -= fabs(eG[b*64 + 16*s + 15]);
    if (tid < 16) dd[tid] = dv;
    if (tid < 15) ee[tid] = eG[b*64 + 16*s + tid];
    if (tid == 15) ee[15] = 0.0;
  }
  for (int idx = tid; idx < 16*17; idx += 64) Zt[idx] = 0.0;
  __syncthreads();
  if (tid < 16) Zt[tid*17+tid] = 1.0;
  __syncthreads();

  steqr16<17>(dd, ee, Zt, tid, wc, wsn);
  __syncthreads();

  // store compact 16x16 block + updated d
  for (int idx = tid; idx < 256; idx += 64){
    int r = idx >> 4, c = idx & 15;
    Zg[(size_t)b*4096 + s*256 + idx] = Zt[r*17+c];
  }
  if (tid < 16) dG[b*64 + 16*s + tid] = dd[tid];
}

// ---------------- Phase B3: two independent 16+16 merges ----------------
__global__ __launch_bounds__(64) void merge16_kernel(double* __restrict__ Zg,
                                                     double* __restrict__ dG,
                                                     const double* __restrict__ eG)
{
  __shared__ double Z32[32*33];
  __shared__ double dloc[32];
  __shared__ double zz[32], dl[32], ww[32], mu[32], wt[32];
  __shared__ int idxm[32], sv[32], tl[32], fp[32];
  const int b = blockIdx.x >> 1, h = blockIdx.x & 1;
  const int tid = threadIdx.x;

  for (int idx = tid; idx < 32*33; idx += 64) Z32[idx] = 0.0;
  if (tid < 32) dloc[tid] = dG[b*64 + 32*h + tid];
  __syncthreads();
  for (int idx = tid; idx < 256; idx += 64){
    int r = idx >> 4, c = idx & 15;
    Z32[r*33 + c]           = Zg[(size_t)b*4096 + (2*h)*256   + idx];
    Z32[(16+r)*33 + (16+c)] = Zg[(size_t)b*4096 + (2*h+1)*256 + idx];
  }
  __syncthreads();

  double rho_in = eG[b*64 + 32*h + 15];
  merge_dc<16,33>(Z32, dloc, rho_in, tid, zz, dl, ww, mu, wt, idxm, sv, tl, fp);

  // store 32x32 result to the upper half of Zg[b] (disjoint from the inputs)
  for (int idx = tid; idx < 1024; idx += 64){
    int r = idx >> 5, c = idx & 31;
    Zg[(size_t)b*4096 + 2048 + h*1024 + idx] = Z32[r*33 + c];
  }
  if (tid < 32) dG[b*64 + 32*h + tid] = dloc[tid];
}

// ---------------- Phase B4: 32+32 merge + back-transform + output V ----------------
__global__ __launch_bounds__(64) void merge32_bt_kernel(const double* __restrict__ Zg,
                                                        double* __restrict__ dG,
                                                        const double* __restrict__ eG,
                                                        const double* __restrict__ tauG,
                                                        const double* __restrict__ VlG,
                                                        float* __restrict__ Vt)
{
  __shared__ double Z64[64*65];
  __shared__ double dloc[64], tau_l[64];
  __shared__ double zz[64], dl[64], ww[64], mu[64], wt[64];
  __shared__ int idxm[64], sv[64], tl[64], fp[64];
  const int b = blockIdx.x;
  const int tid = threadIdx.x;

  for (int idx = tid; idx < 64*65; idx += 64) Z64[idx] = 0.0;
  dloc[tid]  = dG[b*64 + tid];
  tau_l[tid] = tauG[b*64 + tid];
  __syncthreads();
  for (int idx = tid; idx < 1024; idx += 64){
    int r = idx >> 5, c = idx & 31;
    Z64[r*65 + c]           = Zg[(size_t)b*4096 + 2048 + idx];
    Z64[(32+r)*65 + (32+c)] = Zg[(size_t)b*4096 + 3072 + idx];
  }
  __syncthreads();

  double rho_in = eG[b*64 + 31];
  merge_dc<32,65>(Z64, dloc, rho_in, tid, zz, dl, ww, mu, wt, idxm, sv, tl, fp);

  // back-transform: Z := H1...H63 * Z (thread owns column tid; Vl via uniform loads)
  {
    const double* vb = VlG + (size_t)b*63*64;
    int j = tid;
    for (int i = 62; i >= 0; --i){
      double taui = tau_l[i];
      if (taui == 0.0) continue;
      const double* vi = vb + i*64;
      double w = Z64[(i+1)*65 + j];                 // vi[i+1] == 1
      for (int r = i+2; r < 64; ++r) w += vi[r]*Z64[r*65 + j];
      w *= taui;
      Z64[(i+1)*65 + j] -= w;
      for (int r = i+2; r < 64; ++r) Z64[r*65 + j] -= vi[r]*w;
    }
  }
  __syncthreads();

  // Vt[b][c][k] = V[c][63-k]  (descending top-32)
  for (int idx = tid; idx < 2048; idx += 64){
    int c2 = idx >> 5, k = idx & 31;
    Vt[(size_t)b*2048 + idx] = (float)Z64[c2*65 + (63-k)];
  }
}

// ---------------- Phase C: projection ----------------
__global__ __launch_bounds__(256) void proj_kernel(const float* __restrict__ x,
                                                   const float* __restrict__ Vt,
                                                   const float* __restrict__ meanf,
                                                   float* __restrict__ out)
{
  __shared__ float Vs[64][32];
  __shared__ float ms[64];
  const int b = blockIdx.x >> 8;
  const int rb = blockIdx.x & 255;
  const int tid = threadIdx.x;
  for (int idx = tid; idx < 2048; idx += 256) ((float*)Vs)[idx] = Vt[(size_t)b*2048 + idx];
  if (tid < 64) ms[tid] = meanf[b*64+tid];
  __syncthreads();
  const size_t row = (size_t)b*65536 + (size_t)rb*256 + tid;
  const float4* xr = (const float4*)(x + row*64);
  float acc[32];
  #pragma unroll
  for (int k = 0; k < 32; ++k) acc[k] = 0.f;
  #pragma unroll
  for (int c4 = 0; c4 < 16; ++c4){
    float4 xv = xr[c4];
    float t0 = xv.x - ms[4*c4+0];
    float t1 = xv.y - ms[4*c4+1];
    float t2 = xv.z - ms[4*c4+2];
    float t3 = xv.w - ms[4*c4+3];
    #pragma unroll
    for (int k = 0; k < 32; ++k) acc[k] += t0*Vs[4*c4+0][k];
    #pragma unroll
    for (int k = 0; k < 32; ++k) acc[k] += t1*Vs[4*c4+1][k];
    #pragma unroll
    for (int k = 0; k < 32; ++k) acc[k] += t2*Vs[4*c4+2][k];
    #pragma unroll
    for (int k = 0; k < 32; ++k) acc[k] += t3*Vs[4*c4+3][k];
  }
  float4* op = (float4*)(out + row*32);
  #pragma unroll
  for (int k4 = 0; k4 < 8; ++k4)
    op[k4] = make_float4(acc[4*k4], acc[4*k4+1], acc[4*k4+2], acc[4*k4+3]);
}

extern "C" void kernel_launch(void* const* d_in, const int* in_sizes, int n_in,
                              void* d_out, int out_size, void* d_ws, size_t ws_size,
                              hipStream_t stream)
{
  const float* x = (const float*)d_in[0];
  float* out = (float*)d_out;
  char* ws = (char*)d_ws;
  // ws layout (bytes):
  //   [0,       524288) gram 16x64x64 dbl (atomics; zeroed) -> reused as Zg after tridiag
  //   [524288,  532480) chsum 16x64 dbl (atomics; zeroed)
  //   [532480,  540672) dG   16x64 dbl
  //   [540672,  548864) eG   16x64 dbl
  //   [548864,  557056) tauG 16x64 dbl
  //   [557056, 1073152) VlG  16x63x64 dbl (reflectors, transposed: Vl[b][i][r])
  //   [1073152,1204224) Vt   16x64x32 f32
  //   [1204224,1208320) mean 16x64 f32
  double* gram  = (double*)(ws);
  double* Zg    = (double*)(ws);             // alias: gram dead after tridiag_kernel
  double* chsum = (double*)(ws + 524288);
  double* dG    = (double*)(ws + 532480);
  double* eG    = (double*)(ws + 540672);
  double* tauG  = (double*)(ws + 548864);
  double* VlG   = (double*)(ws + 557056);
  float*  Vt    = (float*) (ws + 1073152);
  float*  mf    = (float*) (ws + 1204224);

  hipMemsetAsync(ws, 0, 532480, stream);
  cov_kernel     <<<dim3(512),  dim3(256), 0, stream>>>(x, gram, chsum);
  tridiag_kernel <<<dim3(16),   dim3(64),  0, stream>>>(gram, chsum, dG, eG, tauG, VlG, mf);
  steqr_kernel   <<<dim3(64),   dim3(64),  0, stream>>>(dG, eG, Zg);
  merge16_kernel <<<dim3(32),   dim3(64),  0, stream>>>(Zg, dG, eG);
  merge32_bt_kernel<<<dim3(16), dim3(64),  0, stream>>>(Zg, dG, eG, tauG, VlG, Vt);
  proj_kernel    <<<dim3(4096), dim3(256), 0, stream>>>(x, Vt, mf, out);
}